// Round 13
// baseline (296.882 us; speedup 1.0000x reference)
//
#include <hip/hip_runtime.h>

#define C_DIM 256
#define N_SP  4096
#define B_DIM 2
#define CPG   8
#define EPS_GN 1e-5f
#define CN ((size_t)C_DIM * N_SP)

typedef unsigned short ushort_t;
typedef unsigned int uint_t;
typedef __attribute__((ext_vector_type(4))) float f32x4;
typedef __attribute__((ext_vector_type(16))) float f32x16;
typedef __attribute__((ext_vector_type(4))) unsigned int u32x4;
typedef __attribute__((ext_vector_type(8))) short bf16x8;

// HW packed f32->bf16 (RNE)
__device__ inline uint_t pkbf(float a, float b) {
  uint_t r;
  asm("v_cvt_pk_bf16_f32 %0, %1, %2" : "=v"(r) : "v"(a), "v"(b));
  return r;
}
__device__ inline float bf2f(uint_t u) {
  union { uint_t u; float f; } v; v.u = u << 16; return v.f;
}

#define GLOAD16(src, dst) __builtin_amdgcn_global_load_lds( \
    (const __attribute__((address_space(1))) unsigned int*)(src), \
    (__attribute__((address_space(3))) unsigned int*)(dst), 16, 0, 0)

// ---------------------------------------------------------------------------
// Weight conversion: 4 x (256x256) fp32 -> bf16 concatenated [wq;wk;wv;wp].
// ---------------------------------------------------------------------------
__global__ __launch_bounds__(256) void wcvt_kernel(const float* __restrict__ wq,
    const float* __restrict__ wk, const float* __restrict__ wv,
    const float* __restrict__ wp, ushort_t* __restrict__ o) {
  int gid = blockIdx.x * 256 + threadIdx.x;
  int i4 = gid * 4;
  const float* s = (i4 < 65536) ? wq : (i4 < 131072) ? wk : (i4 < 196608) ? wv : wp;
  int off = i4 & 65535;
  float4 v = *(const float4*)(s + off);
  uint2 p; p.x = pkbf(v.x, v.y); p.y = pkbf(v.z, v.w);
  *(uint2*)&o[i4] = p;
}

// ---------------------------------------------------------------------------
// GroupNorm stats: grid (64, 4) -> partial (sum, sumsq) per (bg, quarter).
// ---------------------------------------------------------------------------
__global__ __launch_bounds__(256) void gn_stats(const float* __restrict__ x,
    float* __restrict__ part) {
  const int bg = blockIdx.x, sub = blockIdx.y;
  const float* xp = x + (size_t)bg * CPG * N_SP + (size_t)sub * (CPG * N_SP / 4);
  const int tid = threadIdx.x;
  float s = 0.f, ss = 0.f;
  for (int i = tid; i < CPG * N_SP / 4; i += 256) {
    float v = xp[i];
    s += v; ss += v * v;
  }
#pragma unroll
  for (int off = 32; off > 0; off >>= 1) {
    s  += __shfl_down(s, off);
    ss += __shfl_down(ss, off);
  }
  __shared__ float rs[4], rss[4];
  const int wv = tid >> 6, ln = tid & 63;
  if (ln == 0) { rs[wv] = s; rss[wv] = ss; }
  __syncthreads();
  if (tid == 0) {
    part[(bg * 4 + sub) * 2]     = rs[0] + rs[1] + rs[2] + rs[3];
    part[(bg * 4 + sub) * 2 + 1] = rss[0] + rss[1] + rss[2] + rss[3];
  }
}

// ---------------------------------------------------------------------------
// GroupNorm apply -> hT bf16 [B][N][C]. grid (64, 16): (bg, n-chunk of 256).
// ---------------------------------------------------------------------------
__global__ __launch_bounds__(256) void gn_apply(const float* __restrict__ x,
    const float* __restrict__ part, const float* __restrict__ w,
    const float* __restrict__ bgn, ushort_t* __restrict__ hT) {
  const int bg = blockIdx.x;
  const int b = bg >> 5, g = bg & 31;
  const int n0 = blockIdx.y * 256;
  const int tid = threadIdx.x;
  float S = 0.f, SS = 0.f;
#pragma unroll
  for (int i = 0; i < 4; ++i) {
    S  += part[(bg * 4 + i) * 2];
    SS += part[(bg * 4 + i) * 2 + 1];
  }
  const float mean = S / (float)(CPG * N_SP);
  const float var  = SS / (float)(CPG * N_SP) - mean * mean;
  const float rstd = rsqrtf(var + EPS_GN);
  float sc[8], sh[8];
#pragma unroll
  for (int c = 0; c < 8; ++c) {
    sc[c] = w[g * 8 + c] * rstd;
    sh[c] = bgn[g * 8 + c] - mean * sc[c];
  }
  __shared__ float tile[8][256];
  const float* xp = x + ((size_t)b * C_DIM + (size_t)g * CPG) * N_SP;
  for (int i = tid; i < 8 * 256; i += 256) {
    int cc = i >> 8, n = i & 255;
    tile[cc][n] = xp[(size_t)cc * N_SP + n0 + n];
  }
  __syncthreads();
  u32x4 pk4;
#pragma unroll
  for (int p = 0; p < 4; ++p)
    pk4[p] = pkbf(tile[2 * p][tid] * sc[2 * p] + sh[2 * p],
                  tile[2 * p + 1][tid] * sc[2 * p + 1] + sh[2 * p + 1]);
  *(u32x4*)&hT[((size_t)b * N_SP + n0 + tid) * C_DIM + g * 8] = pk4;
}

// ---------------------------------------------------------------------------
// MFMA GEMM, k-contiguous bf16 operands (verified round 4/5).
// ---------------------------------------------------------------------------
template <int MODE>
__global__ __launch_bounds__(256) void mgemm(
    const ushort_t* __restrict__ A, const ushort_t* __restrict__ Bm,
    const float* __restrict__ biasA, const float* __restrict__ biasB,
    ushort_t* __restrict__ outB, float* __restrict__ outF,
    const float* __restrict__ R, int aStride, int bStride, int ldo,
    size_t obStride) {
  __shared__ __align__(16) ushort_t a_lds[128 * 64];
  __shared__ __align__(16) ushort_t b_lds[128 * 64];
  const int bz = blockIdx.z;
  const ushort_t* Ab = A + (size_t)bz * aStride;
  const ushort_t* Bb = Bm + (size_t)bz * bStride;
  const int bm = blockIdx.y * 128, bn = blockIdx.x * 128;
  const int tid = threadIdx.x, wv = tid >> 6, ln = tid & 63;
  const int lo = ln & 15, g = ln >> 4;
  const int wr = wv >> 1, wc = wv & 1;

  f32x4 acc[4][4];
#pragma unroll
  for (int i = 0; i < 4; ++i)
#pragma unroll
    for (int j = 0; j < 4; ++j) acc[i][j] = (f32x4)(0.f);

  float bcol[4];
  float brow = 0.f;
  if (MODE == 0) {
#pragma unroll
    for (int ct = 0; ct < 4; ++ct) {
      int col = bn + wc * 64 + ct * 16 + lo;
      bcol[ct] = (col < 256) ? biasA[col] : biasB[col - 256];
    }
  } else {
    brow = biasA[bm + wr * 64 + ln];
  }

  for (int k0 = 0; k0 < C_DIM; k0 += 64) {
#pragma unroll
    for (int i = 0; i < 4; ++i) {
      int r0 = wv * 32 + i * 8;
      int row = r0 + (ln >> 3);
      GLOAD16(Ab + (size_t)(bm + row) * C_DIM + k0 + (((ln & 7) ^ (row & 7)) << 3),
              &a_lds[r0 * 64]);
      GLOAD16(Bb + (size_t)(bn + row) * C_DIM + k0 + (((ln & 7) ^ (row & 7)) << 3),
              &b_lds[r0 * 64]);
    }
    __syncthreads();
    bf16x8 af[4][2], bfr[4][2];
#pragma unroll
    for (int rt = 0; rt < 4; ++rt)
#pragma unroll
      for (int ks = 0; ks < 2; ++ks) {
        int row = wr * 64 + rt * 16 + lo;
        af[rt][ks] = *(const bf16x8*)&a_lds[row * 64 + (((ks * 4 + g) ^ (row & 7)) << 3)];
      }
#pragma unroll
    for (int ct = 0; ct < 4; ++ct)
#pragma unroll
      for (int ks = 0; ks < 2; ++ks) {
        int col = wc * 64 + ct * 16 + lo;
        bfr[ct][ks] = *(const bf16x8*)&b_lds[col * 64 + (((ks * 4 + g) ^ (col & 7)) << 3)];
      }
    __builtin_amdgcn_s_setprio(1);
#pragma unroll
    for (int ks = 0; ks < 2; ++ks)
#pragma unroll
      for (int rt = 0; rt < 4; ++rt)
#pragma unroll
        for (int ct = 0; ct < 4; ++ct)
          acc[rt][ct] = __builtin_amdgcn_mfma_f32_16x16x32_bf16(af[rt][ks], bfr[ct][ks], acc[rt][ct], 0, 0, 0);
    __builtin_amdgcn_s_setprio(0);
    __syncthreads();
  }

  float* wbase = (wv < 2 ? (float*)a_lds : (float*)b_lds) + (wv & 1) * 2048;
  const int grow = bm + wr * 64 + ln;
#pragma unroll
  for (int p = 0; p < 2; ++p) {
#pragma unroll
    for (int rt = 0; rt < 4; ++rt)
#pragma unroll
      for (int cth = 0; cth < 2; ++cth) {
        int ct = 2 * p + cth;
#pragma unroll
        for (int r = 0; r < 4; ++r) {
          int lrow = rt * 16 + 4 * g + r;
          int lcol = cth * 16 + lo;
          float v = acc[rt][ct][r];
          if (MODE == 0) v += bcol[ct];
          wbase[lrow * 32 + (lcol ^ ((lrow & 7) << 2))] = v;
        }
      }
    f32x4 buf[8];
#pragma unroll
    for (int cb = 0; cb < 8; ++cb) {
      int off = (4 * cb) ^ ((ln & 7) << 2);
      buf[cb] = *(const f32x4*)&wbase[ln * 32 + off];
    }
    const size_t obase = (size_t)grow * ldo + bn + wc * 64 + p * 32;
    if (MODE == 2) {
      const float* Rb = R + (size_t)bz * CN + obase;
      float* ob = outF + (size_t)bz * CN + obase;
#pragma unroll
      for (int cb = 0; cb < 8; ++cb) {
        f32x4 t = buf[cb];
        f32x4 rv = *(const f32x4*)&Rb[4 * cb];
#pragma unroll
        for (int j = 0; j < 4; ++j) t[j] += brow + rv[j];
        *(f32x4*)&ob[4 * cb] = t;
      }
    } else {
      float badd = (MODE == 0) ? 0.f : brow;
      ushort_t* ob = outB + (size_t)bz * obStride + obase;
      uint_t wpk[16];
#pragma unroll
      for (int k = 0; k < 16; ++k)
        wpk[k] = pkbf(buf[k >> 1][(k & 1) * 2] + badd, buf[k >> 1][(k & 1) * 2 + 1] + badd);
#pragma unroll
      for (int sidx = 0; sidx < 4; ++sidx) {
        u32x4 t;
        t[0] = wpk[4 * sidx]; t[1] = wpk[4 * sidx + 1];
        t[2] = wpk[4 * sidx + 2]; t[3] = wpk[4 * sidx + 3];
        *(u32x4*)&ob[sidx * 8] = t;
      }
    }
    __syncthreads();
  }
}

// ---------------------------------------------------------------------------
// MFMA flash attention v13 — v11/v12 structure (dual-group split-K-in-block,
// correctness-verified twice) with __launch_bounds__(512, 1): the explicit
// ",1" minimum is the annotation pattern that yielded a 256-VGPR zero-spill
// binary in R10; R11's (512,2) and R12's (512) both produced a 128-VGPR
// build that spilled ~120 regs (FETCH 255MB, attn 247us).
// ---------------------------------------------------------------------------
__global__ __launch_bounds__(512, 1) void attn_mfma(
    const ushort_t* __restrict__ qk, const ushort_t* __restrict__ vt,
    ushort_t* __restrict__ pO, float* __restrict__ pml) {
  // [group][ K 16384 | V 16384 | P 4*2048 ] ushorts = 2 x 81920 B = 160 KiB
  __shared__ __align__(16) ushort_t lds_all[2][40960];

  const int ksplit = blockIdx.y;
  const int b  = blockIdx.z;
  const int q0 = blockIdx.x * 128;
  const int tid = threadIdx.x;
  const int wv = tid >> 6;      // 0..7
  const int grp = wv >> 2;      // key-group
  const int wg  = wv & 3;       // wave within group (q-rows wg*32..)
  const int ln = tid & 63;
  const int lq = ln & 31;
  const int lh = ln >> 5;

  const ushort_t* qtb = qk + (size_t)b * N_SP * 512;
  const ushort_t* ktb = qtb + 256;
  const ushort_t* vtb = vt + (size_t)b * CN;

  ushort_t* kb = &lds_all[grp][0];
  ushort_t* vb = &lds_all[grp][16384];
  ushort_t* p_base = &lds_all[grp][32768 + wg * 2048];

  bf16x8 qf[16];
  {
    const ushort_t* qp = qtb + (size_t)(q0 + wg * 32 + lq) * 512 + lh * 8;
#pragma unroll
    for (int ks = 0; ks < 16; ++ks) qf[ks] = *(const bf16x8*)(qp + ks * 16);
  }

  f32x16 oac[8];
#pragma unroll
  for (int i = 0; i < 8; ++i) oac[i] = (f32x16)(0.f);
  float m_run = -1e30f, l_run = 0.f;

  const int kgbase = ksplit * 1024 + grp * 512;
  for (int t = 0; t < 8; ++t) {
    const int k0 = kgbase + t * 64;
    // ---- stage K+V for this group's tile (4 waves of the group partition it)
#pragma unroll
    for (int i = 0; i < 8; ++i) {
      int r0 = wg * 16 + i * 2;
      int m = r0 + (ln >> 5);
      GLOAD16(ktb + (size_t)(k0 + m) * 512 + (((ln & 31) ^ (m & 7)) * 8),
              kb + r0 * 256);
    }
#pragma unroll
    for (int i = 0; i < 8; ++i) {
      int c0 = wg * 64 + i * 8;
      int c = c0 + (ln >> 3);
      GLOAD16(vtb + (size_t)c * N_SP + k0 + (((ln & 7) ^ (c & 7)) * 8),
              vb + c0 * 64);
    }
    __syncthreads();   // B1: vmcnt(0) -> both groups' tiles resident

    // ---- S^T = K Q^T : 2 key-subtiles x 16 k-steps (32 MFMA)
    f32x16 s0 = (f32x16)(0.f), s1 = (f32x16)(0.f);
    __builtin_amdgcn_s_setprio(1);
#pragma unroll
    for (int ks = 0; ks < 16; ++ks) {
      bf16x8 kf0 = *(const bf16x8*)&kb[(lq * 256 + ks * 16 + lh * 8) ^ ((lq & 7) << 3)];
      s0 = __builtin_amdgcn_mfma_f32_32x32x16_bf16(kf0, qf[ks], s0, 0, 0, 0);
      int m1 = 32 + lq;
      bf16x8 kf1 = *(const bf16x8*)&kb[(m1 * 256 + ks * 16 + lh * 8) ^ ((m1 & 7) << 3)];
      s1 = __builtin_amdgcn_mfma_f32_32x32x16_bf16(kf1, qf[ks], s1, 0, 0, 0);
    }
    __builtin_amdgcn_s_setprio(0);

    // ---- lane-local online softmax (query = lq)
    const float scale = 0.0625f;
    float mx[16];
#pragma unroll
    for (int r = 0; r < 16; ++r) mx[r] = fmaxf(s0[r], s1[r]);
#pragma unroll
    for (int r = 0; r < 8; ++r) mx[r] = fmaxf(mx[r], mx[r + 8]);
#pragma unroll
    for (int r = 0; r < 4; ++r) mx[r] = fmaxf(mx[r], mx[r + 4]);
    float pm = fmaxf(fmaxf(mx[0], mx[1]), fmaxf(mx[2], mx[3]));
    pm = fmaxf(pm, __shfl_xor(pm, 32));
    pm *= scale;
    float alpha = 1.f;
    if (!__all(pm <= m_run + 8.f)) {     // defer-max (THR=8)
      float mn = fmaxf(m_run, pm);
      alpha = __expf(m_run - mn);
      m_run = mn;
    }
    // P [32][64] bf16, XOR-swizzled (col ^ ((lq&7)<<3)); packed b64 writes.
    float rsum = 0.f;
#pragma unroll
    for (int g2 = 0; g2 < 4; ++g2) {
      float e00 = __expf(s0[4 * g2 + 0] * scale - m_run);
      float e01 = __expf(s0[4 * g2 + 1] * scale - m_run);
      float e02 = __expf(s0[4 * g2 + 2] * scale - m_run);
      float e03 = __expf(s0[4 * g2 + 3] * scale - m_run);
      float e10 = __expf(s1[4 * g2 + 0] * scale - m_run);
      float e11 = __expf(s1[4 * g2 + 1] * scale - m_run);
      float e12 = __expf(s1[4 * g2 + 2] * scale - m_run);
      float e13 = __expf(s1[4 * g2 + 3] * scale - m_run);
      rsum += ((e00 + e01) + (e02 + e03)) + ((e10 + e11) + (e12 + e13));
      uint2 wa; wa.x = pkbf(e00, e01); wa.y = pkbf(e02, e03);
      *(uint2*)&p_base[lq * 64 + ((8 * g2 + 4 * lh) ^ ((lq & 7) << 3))] = wa;
      uint2 wb2; wb2.x = pkbf(e10, e11); wb2.y = pkbf(e12, e13);
      *(uint2*)&p_base[lq * 64 + ((32 + 8 * g2 + 4 * lh) ^ ((lq & 7) << 3))] = wb2;
    }
    rsum += __shfl_xor(rsum, 32);
    l_run = l_run * alpha + rsum;
    if (!__all(alpha == 1.f)) {
#pragma unroll
      for (int i = 0; i < 8; ++i) oac[i] *= alpha;
    }

    // ---- PV: O^T = V^T P^T : 8 c-subtiles x 4 k-steps (32 MFMA)
    __builtin_amdgcn_s_setprio(1);
#pragma unroll
    for (int ks2 = 0; ks2 < 4; ++ks2) {
      bf16x8 pf = *(const bf16x8*)&p_base[lq * 64 + ((ks2 * 16 + lh * 8) ^ ((lq & 7) << 3))];
#pragma unroll
      for (int ot = 0; ot < 8; ++ot) {
        int c = ot * 32 + lq;
        bf16x8 vf = *(const bf16x8*)&vb[(c * 64 + ks2 * 16 + lh * 8) ^ ((c & 7) << 3)];
        oac[ot] = __builtin_amdgcn_mfma_f32_32x32x16_bf16(vf, pf, oac[ot], 0, 0, 0);
      }
    }
    __builtin_amdgcn_s_setprio(0);
    __syncthreads();   // B2: all LDS reads done before next tile's stage
  }

  // ---- in-block merge of the two key-groups -------------------------------
  // (m,l) exchange via group1's P region (dead after loop).
  float* mlx = (float*)&lds_all[1][32768];   // [2 grp][4 wg][32 q][2]
  if (lh == 0) {
    int idx = (((grp * 4 + wg) * 32) + lq) * 2;
    mlx[idx] = m_run;
    mlx[idx + 1] = l_run;
  }
  __syncthreads();
  float a_self, l_fin, m_fin;
  {
    int idx = ((((grp ^ 1) * 4 + wg) * 32) + lq) * 2;
    float mo = mlx[idx];
    float lo_ = mlx[idx + 1];
    m_fin = fmaxf(m_run, mo);
    a_self = __expf(m_run - m_fin);
    l_fin = l_run * a_self + lo_ * __expf(mo - m_fin);
  }
#pragma unroll
  for (int i = 0; i < 8; ++i) oac[i] *= a_self;
  if (grp == 0 && lh == 0) {
    int qn = q0 + wg * 32 + lq;
    size_t mi = (((size_t)(ksplit * B_DIM + b) * N_SP) + qn) * 2;
    pml[mi] = m_fin;
    pml[mi + 1] = l_fin;
  }
  __syncthreads();   // before reusing K/V regions as transpose scratch

  // Two-pass transpose + sum: each wave-pair (grp 0/1, same wg) shares q rows.
  float* sbA = (float*)&lds_all[0][0] + wg * 4096;   // 16KB per wave
  float* sbB = (float*)&lds_all[1][0] + wg * 4096;
  float* mysb = grp ? sbB : sbA;
  uint_t* pO32 = (uint_t*)pO;
  const size_t rowbase = (((size_t)(ksplit * B_DIM + b) * N_SP) + q0 + wg * 32) * 128;
#pragma unroll
  for (int p = 0; p < 2; ++p) {
#pragma unroll
    for (int ot = 0; ot < 4; ++ot)
#pragma unroll
      for (int r = 0; r < 16; ++r) {
        int cl = (r & 3) + 8 * (r >> 2) + 4 * lh;
        int c_loc = ot * 32 + cl;
        mysb[lq * 128 + (c_loc ^ ((lq & 7) << 2))] = oac[p * 4 + ot][r];
      }
    __syncthreads();
    if (grp == 0) {
      const int q = ln >> 1, half = ln & 1;
#pragma unroll
      for (int j = 0; j < 16; ++j) {
        int off = (half * 64 + 4 * j) ^ ((q & 7) << 2);
        f32x4 va = *(const f32x4*)&sbA[q * 128 + off];
        f32x4 vb4 = *(const f32x4*)&sbB[q * 128 + off];
        f32x4 sum = va + vb4;
        uint2 pk2; pk2.x = pkbf(sum[0], sum[1]); pk2.y = pkbf(sum[2], sum[3]);
        *(uint2*)&pO32[rowbase + (size_t)q * 128 + p * 64 + half * 32 + 2 * j] = pk2;
      }
    }
    __syncthreads();
  }
}

// ---------------------------------------------------------------------------
// Merge 4 split-K partials -> aoT bf16 [B][N][C].
// ---------------------------------------------------------------------------
__global__ __launch_bounds__(256) void merge_kernel(const ushort_t* __restrict__ pO,
    const float* __restrict__ pml, ushort_t* __restrict__ aoT) {
  const int b = blockIdx.y;
  const int n = blockIdx.x * 16 + (threadIdx.x >> 4);
  const int cg = threadIdx.x & 15;
  float mi[4], li[4];
#pragma unroll
  for (int i = 0; i < 4; ++i) {
    size_t o = (((size_t)(i * B_DIM + b) * N_SP) + n) * 2;
    mi[i] = pml[o]; li[i] = pml[o + 1];
  }
  float ms = fmaxf(fmaxf(mi[0], mi[1]), fmaxf(mi[2], mi[3]));
  float wsum = 0.f, wi[4];
#pragma unroll
  for (int i = 0; i < 4; ++i) { wi[i] = __expf(mi[i] - ms); wsum += wi[i] * li[i]; }
  float inv = 1.f / wsum;
  float acc[16] = {};
#pragma unroll
  for (int i = 0; i < 4; ++i) {
    const ushort_t* p = pO + (((size_t)(i * B_DIM + b) * N_SP) + n) * C_DIM + cg * 16;
    u32x4 a = *(const u32x4*)p;
    u32x4 c2 = *(const u32x4*)(p + 8);
#pragma unroll
    for (int j = 0; j < 4; ++j) {
      acc[2 * j]     += wi[i] * bf2f(a[j] & 0xffffu);
      acc[2 * j + 1] += wi[i] * bf2f(a[j] >> 16);
      acc[8 + 2 * j]     += wi[i] * bf2f(c2[j] & 0xffffu);
      acc[8 + 2 * j + 1] += wi[i] * bf2f(c2[j] >> 16);
    }
  }
  ushort_t* ob = aoT + ((size_t)b * N_SP + n) * C_DIM + cg * 16;
  u32x4 o0, o1;
#pragma unroll
  for (int k = 0; k < 4; ++k) o0[k] = pkbf(acc[2 * k] * inv, acc[2 * k + 1] * inv);
#pragma unroll
  for (int k = 0; k < 4; ++k) o1[k] = pkbf(acc[8 + 2 * k] * inv, acc[8 + 2 * k + 1] * inv);
  *(u32x4*)&ob[0] = o0;
  *(u32x4*)&ob[8] = o1;
}

// ---------------------------------------------------------------------------
extern "C" void kernel_launch(void* const* d_in, const int* in_sizes, int n_in,
                              void* d_out, int out_size, void* d_ws, size_t ws_size,
                              hipStream_t stream) {
  const float* x   = (const float*)d_in[0];
  const float* gnw = (const float*)d_in[1];
  const float* gnb = (const float*)d_in[2];
  const float* wq  = (const float*)d_in[3];
  const float* bq  = (const float*)d_in[4];
  const float* wk  = (const float*)d_in[5];
  const float* bk  = (const float*)d_in[6];
  const float* wv  = (const float*)d_in[7];
  const float* bv  = (const float*)d_in[8];
  const float* wp  = (const float*)d_in[9];
  const float* bp  = (const float*)d_in[10];
  float* out = (float*)d_out;

  // ws (bytes): hT 4M | wb 0.5M | qk 8M | vN 4M | aoT 4M | pml 0.25M | pO 16M | gnp
  char* w8 = (char*)d_ws;
  ushort_t* hT  = (ushort_t*)(w8);
  ushort_t* wb  = (ushort_t*)(w8 + (4u << 20));
  ushort_t* qkw = (ushort_t*)(w8 + (4u << 20) + (1u << 19));
  ushort_t* vN  = (ushort_t*)(w8 + (12u << 20) + (1u << 19));
  ushort_t* aoT = (ushort_t*)(w8 + (16u << 20) + (1u << 19));
  float*    pml = (float*)(w8 + (20u << 20) + (1u << 19));
  ushort_t* pO  = (ushort_t*)(w8 + (20u << 20) + (1u << 19) + (1u << 18));
  float*    gnp = (float*)(w8 + (36u << 20) + (1u << 19) + (1u << 18));

  ushort_t* wvb = wb + 131072;
  ushort_t* wpb = wb + 196608;

  wcvt_kernel<<<dim3(256), dim3(256), 0, stream>>>(wq, wk, wv, wp, wb);
  gn_stats<<<dim3(B_DIM * 32, 4), dim3(256), 0, stream>>>(x, gnp);
  gn_apply<<<dim3(B_DIM * 32, 16), dim3(256), 0, stream>>>(x, gnp, gnw, gnb, hT);

  mgemm<0><<<dim3(4, 32, B_DIM), dim3(256), 0, stream>>>(
      hT, wb, bq, bk, qkw, nullptr, nullptr, (int)CN, 0, 512, (size_t)N_SP * 512);
  mgemm<1><<<dim3(32, 2, B_DIM), dim3(256), 0, stream>>>(
      wvb, hT, bv, nullptr, vN, nullptr, nullptr, 0, (int)CN, N_SP, CN);

  attn_mfma<<<dim3(32, 4, B_DIM), dim3(512), 0, stream>>>(qkw, vN, pO, pml);
  merge_kernel<<<dim3(256, B_DIM), dim3(256), 0, stream>>>(pO, pml, aoT);

  mgemm<2><<<dim3(32, 2, B_DIM), dim3(256), 0, stream>>>(
      wpb, aoT, bp, nullptr, nullptr, out, x, 0, (int)CN, N_SP, CN);
}

// Round 17
// 118.147 us; speedup vs baseline: 2.5128x; 2.5128x over previous
//
#include <hip/hip_runtime.h>

#define C_DIM 256
#define N_SP  4096
#define B_DIM 2
#define CPG   8
#define EPS_GN 1e-5f
#define CN ((size_t)C_DIM * N_SP)

typedef unsigned short ushort_t;
typedef unsigned int uint_t;
typedef __attribute__((ext_vector_type(4))) float f32x4;
typedef __attribute__((ext_vector_type(16))) float f32x16;
typedef __attribute__((ext_vector_type(4))) unsigned int u32x4;
typedef __attribute__((ext_vector_type(8))) short bf16x8;

// HW packed f32->bf16 (RNE)
__device__ inline uint_t pkbf(float a, float b) {
  uint_t r;
  asm("v_cvt_pk_bf16_f32 %0, %1, %2" : "=v"(r) : "v"(a), "v"(b));
  return r;
}
__device__ inline float bf2f(uint_t u) {
  union { uint_t u; float f; } v; v.u = u << 16; return v.f;
}

#define GLOAD16(src, dst) __builtin_amdgcn_global_load_lds( \
    (const __attribute__((address_space(1))) unsigned int*)(src), \
    (__attribute__((address_space(3))) unsigned int*)(dst), 16, 0, 0)

// ---------------------------------------------------------------------------
// Weight conversion: 4 x (256x256) fp32 -> bf16 concatenated [wq;wk;wv;wp].
// ---------------------------------------------------------------------------
__global__ __launch_bounds__(256) void wcvt_kernel(const float* __restrict__ wq,
    const float* __restrict__ wk, const float* __restrict__ wv,
    const float* __restrict__ wp, ushort_t* __restrict__ o) {
  int gid = blockIdx.x * 256 + threadIdx.x;
  int i4 = gid * 4;
  const float* s = (i4 < 65536) ? wq : (i4 < 131072) ? wk : (i4 < 196608) ? wv : wp;
  int off = i4 & 65535;
  float4 v = *(const float4*)(s + off);
  uint2 p; p.x = pkbf(v.x, v.y); p.y = pkbf(v.z, v.w);
  *(uint2*)&o[i4] = p;
}

// ---------------------------------------------------------------------------
// GroupNorm stats: grid (64, 4) -> partial (sum, sumsq) per (bg, quarter).
// ---------------------------------------------------------------------------
__global__ __launch_bounds__(256) void gn_stats(const float* __restrict__ x,
    float* __restrict__ part) {
  const int bg = blockIdx.x, sub = blockIdx.y;
  const float* xp = x + (size_t)bg * CPG * N_SP + (size_t)sub * (CPG * N_SP / 4);
  const int tid = threadIdx.x;
  float s = 0.f, ss = 0.f;
  for (int i = tid; i < CPG * N_SP / 4; i += 256) {
    float v = xp[i];
    s += v; ss += v * v;
  }
#pragma unroll
  for (int off = 32; off > 0; off >>= 1) {
    s  += __shfl_down(s, off);
    ss += __shfl_down(ss, off);
  }
  __shared__ float rs[4], rss[4];
  const int wv = tid >> 6, ln = tid & 63;
  if (ln == 0) { rs[wv] = s; rss[wv] = ss; }
  __syncthreads();
  if (tid == 0) {
    part[(bg * 4 + sub) * 2]     = rs[0] + rs[1] + rs[2] + rs[3];
    part[(bg * 4 + sub) * 2 + 1] = rss[0] + rss[1] + rss[2] + rss[3];
  }
}

// ---------------------------------------------------------------------------
// GroupNorm apply -> hT bf16 [B][N][C]. grid (64, 16): (bg, n-chunk of 256).
// ---------------------------------------------------------------------------
__global__ __launch_bounds__(256) void gn_apply(const float* __restrict__ x,
    const float* __restrict__ part, const float* __restrict__ w,
    const float* __restrict__ bgn, ushort_t* __restrict__ hT) {
  const int bg = blockIdx.x;
  const int b = bg >> 5, g = bg & 31;
  const int n0 = blockIdx.y * 256;
  const int tid = threadIdx.x;
  float S = 0.f, SS = 0.f;
#pragma unroll
  for (int i = 0; i < 4; ++i) {
    S  += part[(bg * 4 + i) * 2];
    SS += part[(bg * 4 + i) * 2 + 1];
  }
  const float mean = S / (float)(CPG * N_SP);
  const float var  = SS / (float)(CPG * N_SP) - mean * mean;
  const float rstd = rsqrtf(var + EPS_GN);
  float sc[8], sh[8];
#pragma unroll
  for (int c = 0; c < 8; ++c) {
    sc[c] = w[g * 8 + c] * rstd;
    sh[c] = bgn[g * 8 + c] - mean * sc[c];
  }
  __shared__ float tile[8][256];
  const float* xp = x + ((size_t)b * C_DIM + (size_t)g * CPG) * N_SP;
  for (int i = tid; i < 8 * 256; i += 256) {
    int cc = i >> 8, n = i & 255;
    tile[cc][n] = xp[(size_t)cc * N_SP + n0 + n];
  }
  __syncthreads();
  u32x4 pk4;
#pragma unroll
  for (int p = 0; p < 4; ++p)
    pk4[p] = pkbf(tile[2 * p][tid] * sc[2 * p] + sh[2 * p],
                  tile[2 * p + 1][tid] * sc[2 * p + 1] + sh[2 * p + 1]);
  *(u32x4*)&hT[((size_t)b * N_SP + n0 + tid) * C_DIM + g * 8] = pk4;
}

// ---------------------------------------------------------------------------
// MFMA GEMM, k-contiguous bf16 operands (verified round 4/5).
// ---------------------------------------------------------------------------
template <int MODE>
__global__ __launch_bounds__(256) void mgemm(
    const ushort_t* __restrict__ A, const ushort_t* __restrict__ Bm,
    const float* __restrict__ biasA, const float* __restrict__ biasB,
    ushort_t* __restrict__ outB, float* __restrict__ outF,
    const float* __restrict__ R, int aStride, int bStride, int ldo,
    size_t obStride) {
  __shared__ __align__(16) ushort_t a_lds[128 * 64];
  __shared__ __align__(16) ushort_t b_lds[128 * 64];
  const int bz = blockIdx.z;
  const ushort_t* Ab = A + (size_t)bz * aStride;
  const ushort_t* Bb = Bm + (size_t)bz * bStride;
  const int bm = blockIdx.y * 128, bn = blockIdx.x * 128;
  const int tid = threadIdx.x, wv = tid >> 6, ln = tid & 63;
  const int lo = ln & 15, g = ln >> 4;
  const int wr = wv >> 1, wc = wv & 1;

  f32x4 acc[4][4];
#pragma unroll
  for (int i = 0; i < 4; ++i)
#pragma unroll
    for (int j = 0; j < 4; ++j) acc[i][j] = (f32x4)(0.f);

  float bcol[4];
  float brow = 0.f;
  if (MODE == 0) {
#pragma unroll
    for (int ct = 0; ct < 4; ++ct) {
      int col = bn + wc * 64 + ct * 16 + lo;
      bcol[ct] = (col < 256) ? biasA[col] : biasB[col - 256];
    }
  } else {
    brow = biasA[bm + wr * 64 + ln];
  }

  for (int k0 = 0; k0 < C_DIM; k0 += 64) {
#pragma unroll
    for (int i = 0; i < 4; ++i) {
      int r0 = wv * 32 + i * 8;
      int row = r0 + (ln >> 3);
      GLOAD16(Ab + (size_t)(bm + row) * C_DIM + k0 + (((ln & 7) ^ (row & 7)) << 3),
              &a_lds[r0 * 64]);
      GLOAD16(Bb + (size_t)(bn + row) * C_DIM + k0 + (((ln & 7) ^ (row & 7)) << 3),
              &b_lds[r0 * 64]);
    }
    __syncthreads();
    bf16x8 af[4][2], bfr[4][2];
#pragma unroll
    for (int rt = 0; rt < 4; ++rt)
#pragma unroll
      for (int ks = 0; ks < 2; ++ks) {
        int row = wr * 64 + rt * 16 + lo;
        af[rt][ks] = *(const bf16x8*)&a_lds[row * 64 + (((ks * 4 + g) ^ (row & 7)) << 3)];
      }
#pragma unroll
    for (int ct = 0; ct < 4; ++ct)
#pragma unroll
      for (int ks = 0; ks < 2; ++ks) {
        int col = wc * 64 + ct * 16 + lo;
        bfr[ct][ks] = *(const bf16x8*)&b_lds[col * 64 + (((ks * 4 + g) ^ (col & 7)) << 3)];
      }
    __builtin_amdgcn_s_setprio(1);
#pragma unroll
    for (int ks = 0; ks < 2; ++ks)
#pragma unroll
      for (int rt = 0; rt < 4; ++rt)
#pragma unroll
        for (int ct = 0; ct < 4; ++ct)
          acc[rt][ct] = __builtin_amdgcn_mfma_f32_16x16x32_bf16(af[rt][ks], bfr[ct][ks], acc[rt][ct], 0, 0, 0);
    __builtin_amdgcn_s_setprio(0);
    __syncthreads();
  }

  float* wbase = (wv < 2 ? (float*)a_lds : (float*)b_lds) + (wv & 1) * 2048;
  const int grow = bm + wr * 64 + ln;
#pragma unroll
  for (int p = 0; p < 2; ++p) {
#pragma unroll
    for (int rt = 0; rt < 4; ++rt)
#pragma unroll
      for (int cth = 0; cth < 2; ++cth) {
        int ct = 2 * p + cth;
#pragma unroll
        for (int r = 0; r < 4; ++r) {
          int lrow = rt * 16 + 4 * g + r;
          int lcol = cth * 16 + lo;
          float v = acc[rt][ct][r];
          if (MODE == 0) v += bcol[ct];
          wbase[lrow * 32 + (lcol ^ ((lrow & 7) << 2))] = v;
        }
      }
    f32x4 buf[8];
#pragma unroll
    for (int cb = 0; cb < 8; ++cb) {
      int off = (4 * cb) ^ ((ln & 7) << 2);
      buf[cb] = *(const f32x4*)&wbase[ln * 32 + off];
    }
    const size_t obase = (size_t)grow * ldo + bn + wc * 64 + p * 32;
    if (MODE == 2) {
      const float* Rb = R + (size_t)bz * CN + obase;
      float* ob = outF + (size_t)bz * CN + obase;
#pragma unroll
      for (int cb = 0; cb < 8; ++cb) {
        f32x4 t = buf[cb];
        f32x4 rv = *(const f32x4*)&Rb[4 * cb];
#pragma unroll
        for (int j = 0; j < 4; ++j) t[j] += brow + rv[j];
        *(f32x4*)&ob[4 * cb] = t;
      }
    } else {
      float badd = (MODE == 0) ? 0.f : brow;
      ushort_t* ob = outB + (size_t)bz * obStride + obase;
      uint_t wpk[16];
#pragma unroll
      for (int k = 0; k < 16; ++k)
        wpk[k] = pkbf(buf[k >> 1][(k & 1) * 2] + badd, buf[k >> 1][(k & 1) * 2 + 1] + badd);
#pragma unroll
      for (int sidx = 0; sidx < 4; ++sidx) {
        u32x4 t;
        t[0] = wpk[4 * sidx]; t[1] = wpk[4 * sidx + 1];
        t[2] = wpk[4 * sidx + 2]; t[3] = wpk[4 * sidx + 3];
        *(u32x4*)&ob[sidx * 8] = t;
      }
    }
    __syncthreads();
  }
}

// ---------------------------------------------------------------------------
// MFMA flash attention v10 (R10-verified, 118us total / 72us attn):
// 32x32x16 MFMA, 32 q/wave, KT=64, double-buffered K/V, one barrier per
// tile, packed P-writes (ds_write_b64 via cvt_pk), per-g2 exp processing.
// ---------------------------------------------------------------------------
__device__ __forceinline__ void stage_kv(const ushort_t* __restrict__ ktb,
    const ushort_t* __restrict__ vtb, int k0, ushort_t* kbuf, ushort_t* vbuf,
    int wv, int ln) {
#pragma unroll
  for (int i = 0; i < 8; ++i) {
    int m = wv * 16 + i * 2 + (ln >> 5);
    int sl = ln & 31;
    GLOAD16(ktb + (size_t)(k0 + m) * 512 + ((sl ^ (m & 7)) * 8),
            kbuf + (wv * 16 + i * 2) * 256);
  }
#pragma unroll
  for (int i = 0; i < 8; ++i) {
    int c = wv * 64 + i * 8 + (ln >> 3);
    int sl = ln & 7;
    GLOAD16(vtb + (size_t)c * N_SP + k0 + ((sl ^ (c & 7)) * 8),
            vbuf + (wv * 64 + i * 8) * 64);
  }
}

__global__ __launch_bounds__(256, 1) void attn_mfma(
    const ushort_t* __restrict__ qk, const ushort_t* __restrict__ vt,
    ushort_t* __restrict__ pO, float* __restrict__ pml) {
  // layout: k[2][64*256] | v[2][256*64] | p[4][32*72]  = 149504 B
  __shared__ __align__(16) ushort_t lds_all[32768 + 32768 + 9216];

  const int ksplit = blockIdx.y;
  const int b  = blockIdx.z;
  const int q0 = blockIdx.x * 128;
  const int tid = threadIdx.x;
  const int wv = tid >> 6;
  const int ln = tid & 63;
  const int lq = ln & 31;    // query column
  const int lh = ln >> 5;    // k-half selector

  const ushort_t* qtb = qk + (size_t)b * N_SP * 512;
  const ushort_t* ktb = qtb + 256;
  const ushort_t* vtb = vt + (size_t)b * CN;
  ushort_t* p_base = lds_all + 65536 + wv * (32 * 72);

  bf16x8 qf[16];
  {
    const ushort_t* qp = qtb + (size_t)(q0 + wv * 32 + lq) * 512 + lh * 8;
#pragma unroll
    for (int ks = 0; ks < 16; ++ks) qf[ks] = *(const bf16x8*)(qp + ks * 16);
  }

  f32x16 oac[8];
#pragma unroll
  for (int i = 0; i < 8; ++i) oac[i] = (f32x16)(0.f);
  float m_run = -1e30f, l_run = 0.f;

  const int kbase = ksplit * 1024;
  stage_kv(ktb, vtb, kbase, lds_all, lds_all + 32768, wv, ln);
  __syncthreads();   // implicit vmcnt(0): tile 0 resident

  for (int t = 0; t < 16; ++t) {
    const int cur = t & 1;
    ushort_t* kb = lds_all + cur * 16384;
    ushort_t* vb = lds_all + 32768 + cur * 16384;
    if (t + 1 < 16)
      stage_kv(ktb, vtb, kbase + (t + 1) * 64,
               lds_all + (cur ^ 1) * 16384,
               lds_all + 32768 + (cur ^ 1) * 16384, wv, ln);

    // ---- S^T = K Q^T : 2 key-subtiles x 16 k-steps (32 MFMA)
    f32x16 s0 = (f32x16)(0.f), s1 = (f32x16)(0.f);
    __builtin_amdgcn_s_setprio(1);
#pragma unroll
    for (int ks = 0; ks < 16; ++ks) {
      bf16x8 kf0 = *(const bf16x8*)&kb[(lq * 256 + ks * 16 + lh * 8) ^ ((lq & 7) << 3)];
      s0 = __builtin_amdgcn_mfma_f32_32x32x16_bf16(kf0, qf[ks], s0, 0, 0, 0);
      int m1 = 32 + lq;
      bf16x8 kf1 = *(const bf16x8*)&kb[(m1 * 256 + ks * 16 + lh * 8) ^ ((m1 & 7) << 3)];
      s1 = __builtin_amdgcn_mfma_f32_32x32x16_bf16(kf1, qf[ks], s1, 0, 0, 0);
    }
    __builtin_amdgcn_s_setprio(0);

    // ---- lane-local online softmax (query = lq)
    const float scale = 0.0625f;
    float mx[16];
#pragma unroll
    for (int r = 0; r < 16; ++r) mx[r] = fmaxf(s0[r], s1[r]);
#pragma unroll
    for (int r = 0; r < 8; ++r) mx[r] = fmaxf(mx[r], mx[r + 8]);
#pragma unroll
    for (int r = 0; r < 4; ++r) mx[r] = fmaxf(mx[r], mx[r + 4]);
    float pm = fmaxf(fmaxf(mx[0], mx[1]), fmaxf(mx[2], mx[3]));
    pm = fmaxf(pm, __shfl_xor(pm, 32));
    pm *= scale;
    float alpha = 1.f;
    if (!__all(pm <= m_run + 8.f)) {     // defer-max (THR=8)
      float mn = fmaxf(m_run, pm);
      alpha = __expf(m_run - mn);
      m_run = mn;
    }
    // per-g2: 8 exps live at once; pack 4 bf16 -> one ds_write_b64 per half.
    float rsum = 0.f;
#pragma unroll
    for (int g2 = 0; g2 < 4; ++g2) {
      float e00 = __expf(s0[4 * g2 + 0] * scale - m_run);
      float e01 = __expf(s0[4 * g2 + 1] * scale - m_run);
      float e02 = __expf(s0[4 * g2 + 2] * scale - m_run);
      float e03 = __expf(s0[4 * g2 + 3] * scale - m_run);
      float e10 = __expf(s1[4 * g2 + 0] * scale - m_run);
      float e11 = __expf(s1[4 * g2 + 1] * scale - m_run);
      float e12 = __expf(s1[4 * g2 + 2] * scale - m_run);
      float e13 = __expf(s1[4 * g2 + 3] * scale - m_run);
      rsum += ((e00 + e01) + (e02 + e03)) + ((e10 + e11) + (e12 + e13));
      uint2 wa; wa.x = pkbf(e00, e01); wa.y = pkbf(e02, e03);
      *(uint2*)&p_base[lq * 72 + 8 * g2 + 4 * lh] = wa;
      uint2 wb2; wb2.x = pkbf(e10, e11); wb2.y = pkbf(e12, e13);
      *(uint2*)&p_base[lq * 72 + 32 + 8 * g2 + 4 * lh] = wb2;
    }
    rsum += __shfl_xor(rsum, 32);
    l_run = l_run * alpha + rsum;
    if (!__all(alpha == 1.f)) {
#pragma unroll
      for (int i = 0; i < 8; ++i) oac[i] *= alpha;
    }

    // ---- PV: O^T = V^T P^T : 8 c-subtiles x 4 k-steps (32 MFMA)
    __builtin_amdgcn_s_setprio(1);
#pragma unroll
    for (int ks2 = 0; ks2 < 4; ++ks2) {
      bf16x8 pf = *(const bf16x8*)&p_base[lq * 72 + ks2 * 16 + lh * 8];
#pragma unroll
      for (int ot = 0; ot < 8; ++ot) {
        int c = ot * 32 + lq;
        bf16x8 vf = *(const bf16x8*)&vb[(c * 64 + ks2 * 16 + lh * 8) ^ ((c & 7) << 3)];
        oac[ot] = __builtin_amdgcn_mfma_f32_32x32x16_bf16(vf, pf, oac[ot], 0, 0, 0);
      }
    }
    __builtin_amdgcn_s_setprio(0);
    __syncthreads();   // drains stage(t+1) loads; fences buffer reuse
  }

  // ---- epilogue: per-wave 32KB fp32 scratch transpose (reuse k/v LDS)
  float* sb = (float*)lds_all + wv * 8192;
#pragma unroll
  for (int ot = 0; ot < 8; ++ot)
#pragma unroll
    for (int r = 0; r < 16; ++r) {
      int cl = (r & 3) + 8 * (r >> 2) + 4 * lh;
      int c = ot * 32 + cl;
      sb[lq * 256 + (c ^ ((lq & 7) << 2))] = oac[ot][r];
    }
  {
    const int q = ln >> 1, half = ln & 1;
    const size_t row32 = (((size_t)(ksplit * B_DIM + b) * N_SP) + q0 + wv * 32 + q) * 128;
    uint_t* pO32 = (uint_t*)pO;
#pragma unroll
    for (int j = 0; j < 32; ++j) {
      f32x4 v4 = *(const f32x4*)&sb[q * 256 + ((half * 128 + 4 * j) ^ ((q & 7) << 2))];
      uint2 pk2; pk2.x = pkbf(v4[0], v4[1]); pk2.y = pkbf(v4[2], v4[3]);
      *(uint2*)&pO32[row32 + half * 64 + 2 * j] = pk2;
    }
  }
  if (ln < 32) {
    int qn = q0 + wv * 32 + lq;
    size_t mi = (((size_t)(ksplit * B_DIM + b) * N_SP) + qn) * 2;
    pml[mi] = m_run;
    pml[mi + 1] = l_run;
  }
}

// ---------------------------------------------------------------------------
// Merge 4 split-K partials -> aoT bf16 [B][N][C].
// ---------------------------------------------------------------------------
__global__ __launch_bounds__(256) void merge_kernel(const ushort_t* __restrict__ pO,
    const float* __restrict__ pml, ushort_t* __restrict__ aoT) {
  const int b = blockIdx.y;
  const int n = blockIdx.x * 16 + (threadIdx.x >> 4);
  const int cg = threadIdx.x & 15;
  float mi[4], li[4];
#pragma unroll
  for (int i = 0; i < 4; ++i) {
    size_t o = (((size_t)(i * B_DIM + b) * N_SP) + n) * 2;
    mi[i] = pml[o]; li[i] = pml[o + 1];
  }
  float ms = fmaxf(fmaxf(mi[0], mi[1]), fmaxf(mi[2], mi[3]));
  float wsum = 0.f, wi[4];
#pragma unroll
  for (int i = 0; i < 4; ++i) { wi[i] = __expf(mi[i] - ms); wsum += wi[i] * li[i]; }
  float inv = 1.f / wsum;
  float acc[16] = {};
#pragma unroll
  for (int i = 0; i < 4; ++i) {
    const ushort_t* p = pO + (((size_t)(i * B_DIM + b) * N_SP) + n) * C_DIM + cg * 16;
    u32x4 a = *(const u32x4*)p;
    u32x4 c2 = *(const u32x4*)(p + 8);
#pragma unroll
    for (int j = 0; j < 4; ++j) {
      acc[2 * j]     += wi[i] * bf2f(a[j] & 0xffffu);
      acc[2 * j + 1] += wi[i] * bf2f(a[j] >> 16);
      acc[8 + 2 * j]     += wi[i] * bf2f(c2[j] & 0xffffu);
      acc[8 + 2 * j + 1] += wi[i] * bf2f(c2[j] >> 16);
    }
  }
  ushort_t* ob = aoT + ((size_t)b * N_SP + n) * C_DIM + cg * 16;
  u32x4 o0, o1;
#pragma unroll
  for (int k = 0; k < 4; ++k) o0[k] = pkbf(acc[2 * k] * inv, acc[2 * k + 1] * inv);
#pragma unroll
  for (int k = 0; k < 4; ++k) o1[k] = pkbf(acc[8 + 2 * k] * inv, acc[8 + 2 * k + 1] * inv);
  *(u32x4*)&ob[0] = o0;
  *(u32x4*)&ob[8] = o1;
}

// ---------------------------------------------------------------------------
extern "C" void kernel_launch(void* const* d_in, const int* in_sizes, int n_in,
                              void* d_out, int out_size, void* d_ws, size_t ws_size,
                              hipStream_t stream) {
  const float* x   = (const float*)d_in[0];
  const float* gnw = (const float*)d_in[1];
  const float* gnb = (const float*)d_in[2];
  const float* wq  = (const float*)d_in[3];
  const float* bq  = (const float*)d_in[4];
  const float* wk  = (const float*)d_in[5];
  const float* bk  = (const float*)d_in[6];
  const float* wv  = (const float*)d_in[7];
  const float* bv  = (const float*)d_in[8];
  const float* wp  = (const float*)d_in[9];
  const float* bp  = (const float*)d_in[10];
  float* out = (float*)d_out;

  // ws (bytes): hT 4M | wb 0.5M | qk 8M | vN 4M | aoT 4M | pml 0.25M | pO 16M | gnp
  char* w8 = (char*)d_ws;
  ushort_t* hT  = (ushort_t*)(w8);
  ushort_t* wb  = (ushort_t*)(w8 + (4u << 20));
  ushort_t* qkw = (ushort_t*)(w8 + (4u << 20) + (1u << 19));
  ushort_t* vN  = (ushort_t*)(w8 + (12u << 20) + (1u << 19));
  ushort_t* aoT = (ushort_t*)(w8 + (16u << 20) + (1u << 19));
  float*    pml = (float*)(w8 + (20u << 20) + (1u << 19));
  ushort_t* pO  = (ushort_t*)(w8 + (20u << 20) + (1u << 19) + (1u << 18));
  float*    gnp = (float*)(w8 + (36u << 20) + (1u << 19) + (1u << 18));

  ushort_t* wvb = wb + 131072;
  ushort_t* wpb = wb + 196608;

  wcvt_kernel<<<dim3(256), dim3(256), 0, stream>>>(wq, wk, wv, wp, wb);
  gn_stats<<<dim3(B_DIM * 32, 4), dim3(256), 0, stream>>>(x, gnp);
  gn_apply<<<dim3(B_DIM * 32, 16), dim3(256), 0, stream>>>(x, gnp, gnw, gnb, hT);

  mgemm<0><<<dim3(4, 32, B_DIM), dim3(256), 0, stream>>>(
      hT, wb, bq, bk, qkw, nullptr, nullptr, (int)CN, 0, 512, (size_t)N_SP * 512);
  mgemm<1><<<dim3(32, 2, B_DIM), dim3(256), 0, stream>>>(
      wvb, hT, bv, nullptr, vN, nullptr, nullptr, 0, (int)CN, N_SP, CN);

  attn_mfma<<<dim3(32, 4, B_DIM), dim3(256), 0, stream>>>(qkw, vN, pO, pml);
  merge_kernel<<<dim3(256, B_DIM), dim3(256), 0, stream>>>(pO, pml, aoT);

  mgemm<2><<<dim3(32, 2, B_DIM), dim3(256), 0, stream>>>(
      wpb, aoT, bp, nullptr, nullptr, out, x, 0, (int)CN, N_SP, CN);
}